// Round 11
// baseline (411.213 us; speedup 1.0000x reference)
//
#include <hip/hip_runtime.h>
#include <math.h>

#define NHEAD 4
#define DHEAD 32
#define NPIX  4096
#define CIN   128

typedef __bf16 bf16_t;
typedef __bf16 bf16x8 __attribute__((ext_vector_type(8)));
typedef __bf16 bf16x4 __attribute__((ext_vector_type(4)));
typedef float  f32x4  __attribute__((ext_vector_type(4)));

// 1/sqrt(32) * log2(e): folded into q weights so softmax exp is bare exp2.
constexpr float QSCALE = 0.17677669529663687f * 1.4426950408889634f;

// ---------------------------------------------------------------------------
// prep_swz: cast weights to bf16 in MFMA-fragment order (wave-contiguous 1KB
// frag loads). wq_s: 24 oc-tiles of 16 rows (q tiles 0..7 pre-scaled);
// wo_s: 8 oc-tiles. frag addr = ((ot*4 + k)*64 + lane)*8.  [verified r9/r10]
// ---------------------------------------------------------------------------
__global__ void __launch_bounds__(256) prep_swz(
    const float* __restrict__ wqkv, const float* __restrict__ wout,
    ushort* __restrict__ wq_s, ushort* __restrict__ wo_s) {
  const int gid = blockIdx.x * 256 + threadIdx.x;     // 0..8191
  const int lane = gid & 63, n = lane & 15, quad = (lane >> 4) & 3;
  if (gid < 6144) {
    const int ot = gid >> 8, k = (gid >> 6) & 3;      // ot 0..23
    const float sc = (ot < 8) ? QSCALE : 1.f;
    const float* src = wqkv + (size_t)(ot * 16 + n) * CIN + k * 32 + quad * 8;
    bf16x8 o;
#pragma unroll
    for (int e = 0; e < 8; ++e) o[e] = (bf16_t)(src[e] * sc);
    *(bf16x8*)(wq_s + (size_t)gid * 8) = o;
  } else {
    const int oid = gid - 6144;
    const int ot = oid >> 8, k = (oid >> 6) & 3;      // ot 0..7
    const float* src = wout + (size_t)(ot * 16 + n) * CIN + k * 32 + quad * 8;
    bf16x8 o;
#pragma unroll
    for (int e = 0; e < 8; ++e) o[e] = (bf16_t)src[e];
    *(bf16x8*)(wo_s + (size_t)oid * 8) = o;
  }
}

// ---------------------------------------------------------------------------
// QKV projection (unchanged from r10 — verified). 512 blocks x 256 thr.
// q/k -> [bh][p][d] bf16; v -> vT[bh][d][p] bf16 (swapped mfma operands).
// ---------------------------------------------------------------------------
__global__ void __launch_bounds__(256) qkv_mfma(
    const float* __restrict__ x, const ushort* __restrict__ wq_s,
    ushort* __restrict__ qb, ushort* __restrict__ kb, ushort* __restrict__ vT) {
  __shared__ ushort Xls[32 * 136];
  const int blk = blockIdx.x, tid = threadIdx.x;
  const int wave = tid >> 6, lane = tid & 63;
  const int n = lane & 15, quad = lane >> 4;
  const int bb = blk >> 7;             // batch
  const int p0 = (blk & 127) * 32;     // 32-px tile

  {  // stage x[bb][c][p0..p0+31] -> Xls[p][c] bf16 (4x4 transpose)
    const int pc = tid & 7, c0 = (tid >> 3) * 4;
    const float* xp = x + ((size_t)bb * CIN + c0) * NPIX + p0 + pc * 4;
    float4 r0 = *(const float4*)xp;
    float4 r1 = *(const float4*)(xp + NPIX);
    float4 r2 = *(const float4*)(xp + 2 * NPIX);
    float4 r3 = *(const float4*)(xp + 3 * NPIX);
    bf16x4 w0 = {(bf16_t)r0.x, (bf16_t)r1.x, (bf16_t)r2.x, (bf16_t)r3.x};
    bf16x4 w1 = {(bf16_t)r0.y, (bf16_t)r1.y, (bf16_t)r2.y, (bf16_t)r3.y};
    bf16x4 w2 = {(bf16_t)r0.z, (bf16_t)r1.z, (bf16_t)r2.z, (bf16_t)r3.z};
    bf16x4 w3 = {(bf16_t)r0.w, (bf16_t)r1.w, (bf16_t)r2.w, (bf16_t)r3.w};
    *(bf16x4*)&Xls[(pc * 4 + 0) * 136 + c0] = w0;
    *(bf16x4*)&Xls[(pc * 4 + 1) * 136 + c0] = w1;
    *(bf16x4*)&Xls[(pc * 4 + 2) * 136 + c0] = w2;
    *(bf16x4*)&Xls[(pc * 4 + 3) * 136 + c0] = w3;
  }
  __syncthreads();

  bf16x8 xf[2][4];                     // [px-tile nt][k]
#pragma unroll
  for (int nt = 0; nt < 2; ++nt)
#pragma unroll
    for (int k = 0; k < 4; ++k)
      xf[nt][k] = *(const bf16x8*)&Xls[(nt * 16 + n) * 136 + k * 32 + quad * 8];

#pragma unroll
  for (int mt = 0; mt < 6; ++mt) {     // wave covers 96 oc = 6 tiles
    const int ot = wave * 6 + mt;      // 0..23
    const int type = ot >> 3;          // 0=q 1=k 2=v
    const int wt = ot & 7, head = wt >> 1, d0 = (wt & 1) * 16;
    const int bh = bb * NHEAD + head;
    bf16x8 wf4[4];
#pragma unroll
    for (int k = 0; k < 4; ++k)
      wf4[k] = *(const bf16x8*)(wq_s + (size_t)((ot * 4 + k) * 64 + lane) * 8);
    f32x4 acc[2] = {{0.f, 0.f, 0.f, 0.f}, {0.f, 0.f, 0.f, 0.f}};
    if (type < 2) {
#pragma unroll
      for (int k = 0; k < 4; ++k)
#pragma unroll
        for (int nt = 0; nt < 2; ++nt)
          acc[nt] = __builtin_amdgcn_mfma_f32_16x16x32_bf16(wf4[k], xf[nt][k], acc[nt], 0, 0, 0);
      ushort* dst = (type == 0) ? qb : kb;
#pragma unroll
      for (int nt = 0; nt < 2; ++nt) {  // C[m=oc][n=px] -> [p][d] b64
        bf16x4 o = {(bf16_t)acc[nt][0], (bf16_t)acc[nt][1],
                    (bf16_t)acc[nt][2], (bf16_t)acc[nt][3]};
        *(bf16x4*)(dst + ((size_t)bh * NPIX + p0 + nt * 16 + n) * DHEAD + d0 + quad * 4) = o;
      }
    } else {
#pragma unroll
      for (int k = 0; k < 4; ++k)
#pragma unroll
        for (int nt = 0; nt < 2; ++nt)
          acc[nt] = __builtin_amdgcn_mfma_f32_16x16x32_bf16(xf[nt][k], wf4[k], acc[nt], 0, 0, 0);
#pragma unroll
      for (int nt = 0; nt < 2; ++nt) {  // C[m=px][n=d] -> vT[d][p] b64
        bf16x4 o = {(bf16_t)acc[nt][0], (bf16_t)acc[nt][1],
                    (bf16_t)acc[nt][2], (bf16_t)acc[nt][3]};
        *(bf16x4*)(vT + ((size_t)bh * DHEAD + d0 + n) * NPIX + p0 + nt * 16 + quad * 4) = o;
      }
    }
  }
}

// ---------------------------------------------------------------------------
// Flash attention v7: r4's proven 128q-wave shape, key-split js=8 (512 keys
// per wave). Total K/V traffic, exp2 count, MFMA count INVARIANT vs r4 —
// only per-wave work halves and wave count doubles: 4096 waves = 16 waves/CU
// (4 blocks/CU via __launch_bounds__(256,4), VGPR<=128). O-partials stored
// bf16 (combined ao is cast to bf16 downstream anyway; summing 8 rounded
// partials has smaller error than one rounding), l in f32 -> part bytes
// unchanged vs r10. grid (8 qblocks, 8 js, 16 bh), block 256.
// ---------------------------------------------------------------------------
__device__ __forceinline__ void ft_load(const ushort* kb0, const ushort* vb0,
                                        int t, bf16x8* kf, bf16x8* vf) {
#pragma unroll
  for (int p = 0; p < 2; ++p) {
#pragma unroll
    for (int s = 0; s < 2; ++s)
      kf[p * 2 + s] = *(const bf16x8*)(kb0 + (size_t)(t * 64 + p * 32 + s * 4) * DHEAD);
#pragma unroll
    for (int dp = 0; dp < 2; ++dp)
      vf[p * 2 + dp] = *(const bf16x8*)(vb0 + (size_t)dp * 16 * NPIX + t * 64 + p * 32);
  }
}

__device__ __forceinline__ void ft_compute(const bf16x8* qf, const bf16x8* kf,
                                           const bf16x8* vf, const bf16x8 ones,
                                           f32x4 O[8][2], f32x4* Ol) {
  const f32x4 zero = {0.f, 0.f, 0.f, 0.f};
#pragma unroll
  for (int p = 0; p < 2; ++p) {
#pragma unroll
    for (int rp = 0; rp < 8; ++rp) {
      f32x4 sa = __builtin_amdgcn_mfma_f32_16x16x32_bf16(kf[p * 2 + 0], qf[rp], zero, 0, 0, 0);
      f32x4 sb = __builtin_amdgcn_mfma_f32_16x16x32_bf16(kf[p * 2 + 1], qf[rp], zero, 0, 0, 0);
      bf16x8 pf;
#pragma unroll
      for (int r = 0; r < 4; ++r) {
        pf[r]     = (bf16_t)__builtin_amdgcn_exp2f(sa[r]);
        pf[r + 4] = (bf16_t)__builtin_amdgcn_exp2f(sb[r]);
      }
      O[rp][0] = __builtin_amdgcn_mfma_f32_16x16x32_bf16(pf, vf[p * 2 + 0], O[rp][0], 0, 0, 0);
      O[rp][1] = __builtin_amdgcn_mfma_f32_16x16x32_bf16(pf, vf[p * 2 + 1], O[rp][1], 0, 0, 0);
      Ol[rp]   = __builtin_amdgcn_mfma_f32_16x16x32_bf16(pf, ones, Ol[rp], 0, 0, 0);
    }
  }
}

__global__ void __launch_bounds__(256, 4) flash_mfma(
    const ushort* __restrict__ qb, const ushort* __restrict__ kbuf,
    const ushort* __restrict__ vTb, ushort* __restrict__ pO,
    float* __restrict__ pl) {
  const int tid = threadIdx.x, wave = tid >> 6, lane = tid & 63;
  const int n = lane & 15, quad = lane >> 4;
  const int js = blockIdx.y, bh = blockIdx.z;
  const int qrel = blockIdx.x * 512 + wave * 128;

  const ushort* kg = kbuf + (size_t)bh * NPIX * DHEAD;
  const ushort* vg = vTb + (size_t)bh * DHEAD * NPIX;

  bf16x8 qf[8];
#pragma unroll
  for (int rp = 0; rp < 8; ++rp)
    qf[rp] = *(const bf16x8*)(qb +
        ((size_t)bh * NPIX + qrel + rp * 16 + n) * DHEAD + quad * 8);

  f32x4 O[8][2], Ol[8];
#pragma unroll
  for (int rp = 0; rp < 8; ++rp) {
    O[rp][0] = (f32x4){0.f, 0.f, 0.f, 0.f};
    O[rp][1] = (f32x4){0.f, 0.f, 0.f, 0.f};
    Ol[rp]   = (f32x4){0.f, 0.f, 0.f, 0.f};
  }
  const bf16_t one = (bf16_t)1.0f;
  const bf16x8 ones = {one, one, one, one, one, one, one, one};

  // permuted K row: pi(n) = (n>>2)*8 + (n&3); quad gives the d-offset
  const int pk = ((n >> 2) << 3) | (n & 3);
  const ushort* kb0 = kg + (size_t)(js * 512 + pk) * DHEAD + quad * 8;
  const ushort* vb0 = vg + (size_t)n * NPIX + js * 512 + quad * 8;

  bf16x8 kA[4], vA[4], kB[4], vB[4];
  ft_load(kb0, vb0, 0, kA, vA);
#pragma unroll 1
  for (int t = 0; t < 8; t += 2) {
    ft_load(kb0, vb0, t + 1, kB, vB);
    ft_compute(qf, kA, vA, ones, O, Ol);
    if (t + 2 < 8) ft_load(kb0, vb0, t + 2, kA, vA);
    ft_compute(qf, kB, vB, ones, O, Ol);
  }

  ushort* pOb = pO + ((size_t)js * 65536 + (size_t)bh * NPIX + qrel) * 32;
  float*  plb = pl + (size_t)js * 65536 + (size_t)bh * NPIX + qrel;
#pragma unroll
  for (int rp = 0; rp < 8; ++rp)
#pragma unroll
    for (int r = 0; r < 4; ++r) {
      const int q = rp * 16 + quad * 4 + r;
      pOb[(size_t)q * 32 + n]      = __builtin_bit_cast(ushort, (bf16_t)O[rp][0][r]);
      pOb[(size_t)q * 32 + 16 + n] = __builtin_bit_cast(ushort, (bf16_t)O[rp][1][r]);
      if (n == 0) plb[q] = Ol[rp][r];
    }
}

// ---------------------------------------------------------------------------
// out_fused v2: cooperative combine of the 8 key-split partials ONCE per
// block (r10 read part 4x redundantly: 151 MB; now 33.5 MB bf16), normalized
// bf16 ao staged in LDS, then B-frag reads + out-projection MFMA + bias.
// 512 blocks x 256 thr; block = (batch, 32-px tile); wave = 32 oc x 32 px.
// ---------------------------------------------------------------------------
__global__ void __launch_bounds__(256) out_fused(
    const ushort* __restrict__ pO, const float* __restrict__ pl,
    const ushort* __restrict__ wo_s, const float* __restrict__ bias,
    float* __restrict__ out) {
  __shared__ ushort AOls[32 * 136];
  const int blk = blockIdx.x, tid = threadIdx.x;
  const int wave = tid >> 6, lane = tid & 63;
  const int n = lane & 15, quad = lane >> 4;
  const int bb = blk >> 7;
  const int p0 = (blk & 127) * 32;
  const int oc0 = wave * 32;

  bf16x8 wf[2][4];
#pragma unroll
  for (int mt = 0; mt < 2; ++mt)
#pragma unroll
    for (int k = 0; k < 4; ++k)
      wf[mt][k] = *(const bf16x8*)(wo_s + (size_t)(((wave * 2 + mt) * 4 + k) * 64 + lane) * 8);

  // cooperative combine: thread = (px8 = tid>>3, c8 = tid&7 -> head, d-half)
  {
    const int px8 = tid >> 3, c8 = tid & 7;
    const int h = c8 >> 1, dh = (c8 & 1) * 16;
    const size_t rowbase = (size_t)(bb * NHEAD + h) * NPIX + p0 + px8;
    float s[16];
#pragma unroll
    for (int e = 0; e < 16; ++e) s[e] = 0.f;
    float l = 0.f;
#pragma unroll
    for (int js = 0; js < 8; ++js) {
      const ushort* po = pO + ((size_t)js * 65536 + rowbase) * 32 + dh;
      bf16x8 a = *(const bf16x8*)po;
      bf16x8 b = *(const bf16x8*)(po + 8);
#pragma unroll
      for (int e = 0; e < 8; ++e) {
        s[e]     += (float)a[e];
        s[8 + e] += (float)b[e];
      }
      l += pl[(size_t)js * 65536 + rowbase];
    }
    const float inv = 1.f / l;
    bf16x8 o0, o1;
#pragma unroll
    for (int e = 0; e < 8; ++e) {
      o0[e] = (bf16_t)(s[e] * inv);
      o1[e] = (bf16_t)(s[8 + e] * inv);
    }
    ushort* dstl = &AOls[px8 * 136 + c8 * 16];
    *(bf16x8*)dstl = o0;
    *(bf16x8*)(dstl + 8) = o1;
  }
  __syncthreads();

  bf16x8 bfr[2][4];                    // [nt][k] from LDS (shared, not 4x)
#pragma unroll
  for (int nt = 0; nt < 2; ++nt)
#pragma unroll
    for (int k = 0; k < 4; ++k)
      bfr[nt][k] = *(const bf16x8*)&AOls[(nt * 16 + n) * 136 + k * 32 + quad * 8];

  f32x4 acc[2][2];
#pragma unroll
  for (int mt = 0; mt < 2; ++mt)
#pragma unroll
    for (int nt = 0; nt < 2; ++nt) acc[mt][nt] = (f32x4){0.f, 0.f, 0.f, 0.f};
#pragma unroll
  for (int k = 0; k < 4; ++k)
#pragma unroll
    for (int mt = 0; mt < 2; ++mt)
#pragma unroll
      for (int nt = 0; nt < 2; ++nt)
        acc[mt][nt] = __builtin_amdgcn_mfma_f32_16x16x32_bf16(
            wf[mt][k], bfr[nt][k], acc[mt][nt], 0, 0, 0);

#pragma unroll
  for (int mt = 0; mt < 2; ++mt) {
    const int oc = oc0 + mt * 16 + quad * 4;
#pragma unroll
    for (int nt = 0; nt < 2; ++nt)
#pragma unroll
      for (int r = 0; r < 4; ++r)
        out[((size_t)bb * CIN + oc + r) * NPIX + p0 + nt * 16 + n] =
            acc[mt][nt][r] + bias[oc + r];
  }
}

// ---------------------------------------------------------------------------
extern "C" void kernel_launch(void* const* d_in, const int* in_sizes, int n_in,
                              void* d_out, int out_size, void* d_ws, size_t ws_size,
                              hipStream_t stream) {
  const float* x     = (const float*)d_in[0];   // [4,128,64,64]
  const float* w_qkv = (const float*)d_in[1];   // [384,128]
  const float* w_out = (const float*)d_in[2];   // [128,128]
  const float* b_out = (const float*)d_in[3];   // [128]
  float* out = (float*)d_out;                   // [4,128,64,64]

  // ws (bytes): qb 0 | kb 4M | vT 8M | wq_s 12M (96K) | wo_s +256K (32K)
  //             | pl 12.75M (2M) | pO 15M (33.5M)   (~48.6 MB total)
  char* base = (char*)d_ws;
  ushort* qb   = (ushort*)base;
  ushort* kb   = (ushort*)(base + (size_t)4 * 1024 * 1024);
  ushort* vT   = (ushort*)(base + (size_t)8 * 1024 * 1024);
  ushort* wq_s = (ushort*)(base + (size_t)12 * 1024 * 1024);
  ushort* wo_s = (ushort*)(base + (size_t)12 * 1024 * 1024 + 256 * 1024);
  float*  pl   = (float*)(base + (size_t)12 * 1024 * 1024 + 768 * 1024);
  ushort* pO   = (ushort*)(base + (size_t)15 * 1024 * 1024);

  prep_swz<<<dim3(32), 256, 0, stream>>>(w_qkv, w_out, wq_s, wo_s);
  qkv_mfma<<<dim3(512), 256, 0, stream>>>(x, wq_s, qb, kb, vT);
  flash_mfma<<<dim3(8, 8, 16), 256, 0, stream>>>(qb, kb, vT, pO, pl);
  out_fused<<<dim3(512), 256, 0, stream>>>(pO, pl, wo_s, b_out, out);
}

// Round 12
// 127.947 us; speedup vs baseline: 3.2139x; 3.2139x over previous
//
#include <hip/hip_runtime.h>
#include <math.h>

#define NHEAD 4
#define DHEAD 32
#define NPIX  4096
#define CIN   128

typedef __bf16 bf16_t;
typedef __bf16 bf16x8 __attribute__((ext_vector_type(8)));
typedef __bf16 bf16x4 __attribute__((ext_vector_type(4)));
typedef float  f32x4  __attribute__((ext_vector_type(4)));

// 1/sqrt(32) * log2(e): folded into q weights so softmax exp is bare exp2.
constexpr float QSCALE = 0.17677669529663687f * 1.4426950408889634f;

// ---------------------------------------------------------------------------
// prep_swz: cast weights to bf16 in MFMA-fragment order.  [r10 verbatim]
// ---------------------------------------------------------------------------
__global__ void __launch_bounds__(256) prep_swz(
    const float* __restrict__ wqkv, const float* __restrict__ wout,
    ushort* __restrict__ wq_s, ushort* __restrict__ wo_s) {
  const int gid = blockIdx.x * 256 + threadIdx.x;     // 0..8191
  const int lane = gid & 63, n = lane & 15, quad = (lane >> 4) & 3;
  if (gid < 6144) {
    const int ot = gid >> 8, k = (gid >> 6) & 3;      // ot 0..23
    const float sc = (ot < 8) ? QSCALE : 1.f;
    const float* src = wqkv + (size_t)(ot * 16 + n) * CIN + k * 32 + quad * 8;
    bf16x8 o;
#pragma unroll
    for (int e = 0; e < 8; ++e) o[e] = (bf16_t)(src[e] * sc);
    *(bf16x8*)(wq_s + (size_t)gid * 8) = o;
  } else {
    const int oid = gid - 6144;
    const int ot = oid >> 8, k = (oid >> 6) & 3;      // ot 0..7
    const float* src = wout + (size_t)(ot * 16 + n) * CIN + k * 32 + quad * 8;
    bf16x8 o;
#pragma unroll
    for (int e = 0; e < 8; ++e) o[e] = (bf16_t)src[e];
    *(bf16x8*)(wo_s + (size_t)oid * 8) = o;
  }
}

// ---------------------------------------------------------------------------
// QKV projection.  [r10 verbatim]
// ---------------------------------------------------------------------------
__global__ void __launch_bounds__(256) qkv_mfma(
    const float* __restrict__ x, const ushort* __restrict__ wq_s,
    ushort* __restrict__ qb, ushort* __restrict__ kb, ushort* __restrict__ vT) {
  __shared__ ushort Xls[32 * 136];
  const int blk = blockIdx.x, tid = threadIdx.x;
  const int wave = tid >> 6, lane = tid & 63;
  const int n = lane & 15, quad = lane >> 4;
  const int bb = blk >> 7;             // batch
  const int p0 = (blk & 127) * 32;     // 32-px tile

  {  // stage x[bb][c][p0..p0+31] -> Xls[p][c] bf16 (4x4 transpose)
    const int pc = tid & 7, c0 = (tid >> 3) * 4;
    const float* xp = x + ((size_t)bb * CIN + c0) * NPIX + p0 + pc * 4;
    float4 r0 = *(const float4*)xp;
    float4 r1 = *(const float4*)(xp + NPIX);
    float4 r2 = *(const float4*)(xp + 2 * NPIX);
    float4 r3 = *(const float4*)(xp + 3 * NPIX);
    bf16x4 w0 = {(bf16_t)r0.x, (bf16_t)r1.x, (bf16_t)r2.x, (bf16_t)r3.x};
    bf16x4 w1 = {(bf16_t)r0.y, (bf16_t)r1.y, (bf16_t)r2.y, (bf16_t)r3.y};
    bf16x4 w2 = {(bf16_t)r0.z, (bf16_t)r1.z, (bf16_t)r2.z, (bf16_t)r3.z};
    bf16x4 w3 = {(bf16_t)r0.w, (bf16_t)r1.w, (bf16_t)r2.w, (bf16_t)r3.w};
    *(bf16x4*)&Xls[(pc * 4 + 0) * 136 + c0] = w0;
    *(bf16x4*)&Xls[(pc * 4 + 1) * 136 + c0] = w1;
    *(bf16x4*)&Xls[(pc * 4 + 2) * 136 + c0] = w2;
    *(bf16x4*)&Xls[(pc * 4 + 3) * 136 + c0] = w3;
  }
  __syncthreads();

  bf16x8 xf[2][4];                     // [px-tile nt][k]
#pragma unroll
  for (int nt = 0; nt < 2; ++nt)
#pragma unroll
    for (int k = 0; k < 4; ++k)
      xf[nt][k] = *(const bf16x8*)&Xls[(nt * 16 + n) * 136 + k * 32 + quad * 8];

#pragma unroll
  for (int mt = 0; mt < 6; ++mt) {     // wave covers 96 oc = 6 tiles
    const int ot = wave * 6 + mt;      // 0..23
    const int type = ot >> 3;          // 0=q 1=k 2=v
    const int wt = ot & 7, head = wt >> 1, d0 = (wt & 1) * 16;
    const int bh = bb * NHEAD + head;
    bf16x8 wf4[4];
#pragma unroll
    for (int k = 0; k < 4; ++k)
      wf4[k] = *(const bf16x8*)(wq_s + (size_t)((ot * 4 + k) * 64 + lane) * 8);
    f32x4 acc[2] = {{0.f, 0.f, 0.f, 0.f}, {0.f, 0.f, 0.f, 0.f}};
    if (type < 2) {
#pragma unroll
      for (int k = 0; k < 4; ++k)
#pragma unroll
        for (int nt = 0; nt < 2; ++nt)
          acc[nt] = __builtin_amdgcn_mfma_f32_16x16x32_bf16(wf4[k], xf[nt][k], acc[nt], 0, 0, 0);
      ushort* dst = (type == 0) ? qb : kb;
#pragma unroll
      for (int nt = 0; nt < 2; ++nt) {  // C[m=oc][n=px] -> [p][d] b64
        bf16x4 o = {(bf16_t)acc[nt][0], (bf16_t)acc[nt][1],
                    (bf16_t)acc[nt][2], (bf16_t)acc[nt][3]};
        *(bf16x4*)(dst + ((size_t)bh * NPIX + p0 + nt * 16 + n) * DHEAD + d0 + quad * 4) = o;
      }
    } else {
#pragma unroll
      for (int k = 0; k < 4; ++k)
#pragma unroll
        for (int nt = 0; nt < 2; ++nt)
          acc[nt] = __builtin_amdgcn_mfma_f32_16x16x32_bf16(xf[nt][k], wf4[k], acc[nt], 0, 0, 0);
#pragma unroll
      for (int nt = 0; nt < 2; ++nt) {  // C[m=px][n=d] -> vT[d][p] b64
        bf16x4 o = {(bf16_t)acc[nt][0], (bf16_t)acc[nt][1],
                    (bf16_t)acc[nt][2], (bf16_t)acc[nt][3]};
        *(bf16x4*)(vT + ((size_t)bh * DHEAD + d0 + n) * NPIX + p0 + nt * 16 + quad * 4) = o;
      }
    }
  }
}

// ---------------------------------------------------------------------------
// Flash attention.  [r4/r10 verbatim — proven 52 us local optimum: wave =
// 128 queries, LDS-free permuted-key S^T trick, ones-MFMA for l, js=4,
// f32 (O,l) partials. grid (8 qblocks, 4 js, 16 bh), block 256.]
// ---------------------------------------------------------------------------
__device__ __forceinline__ void ft_load(const ushort* kb0, const ushort* vb0,
                                        int t, bf16x8* kf, bf16x8* vf) {
#pragma unroll
  for (int p = 0; p < 2; ++p) {
#pragma unroll
    for (int s = 0; s < 2; ++s)
      kf[p * 2 + s] = *(const bf16x8*)(kb0 + (size_t)(t * 64 + p * 32 + s * 4) * DHEAD);
#pragma unroll
    for (int dp = 0; dp < 2; ++dp)
      vf[p * 2 + dp] = *(const bf16x8*)(vb0 + (size_t)dp * 16 * NPIX + t * 64 + p * 32);
  }
}

__device__ __forceinline__ void ft_compute(const bf16x8* qf, const bf16x8* kf,
                                           const bf16x8* vf, const bf16x8 ones,
                                           f32x4 O[8][2], f32x4* Ol) {
  const f32x4 zero = {0.f, 0.f, 0.f, 0.f};
#pragma unroll
  for (int p = 0; p < 2; ++p) {
#pragma unroll
    for (int rp = 0; rp < 8; ++rp) {
      f32x4 sa = __builtin_amdgcn_mfma_f32_16x16x32_bf16(kf[p * 2 + 0], qf[rp], zero, 0, 0, 0);
      f32x4 sb = __builtin_amdgcn_mfma_f32_16x16x32_bf16(kf[p * 2 + 1], qf[rp], zero, 0, 0, 0);
      bf16x8 pf;
#pragma unroll
      for (int r = 0; r < 4; ++r) {
        pf[r]     = (bf16_t)__builtin_amdgcn_exp2f(sa[r]);
        pf[r + 4] = (bf16_t)__builtin_amdgcn_exp2f(sb[r]);
      }
      O[rp][0] = __builtin_amdgcn_mfma_f32_16x16x32_bf16(pf, vf[p * 2 + 0], O[rp][0], 0, 0, 0);
      O[rp][1] = __builtin_amdgcn_mfma_f32_16x16x32_bf16(pf, vf[p * 2 + 1], O[rp][1], 0, 0, 0);
      Ol[rp]   = __builtin_amdgcn_mfma_f32_16x16x32_bf16(pf, ones, Ol[rp], 0, 0, 0);
    }
  }
}

__global__ void __launch_bounds__(256, 2) flash_mfma(
    const ushort* __restrict__ qb, const ushort* __restrict__ kbuf,
    const ushort* __restrict__ vTb, float* __restrict__ part) {
  const int tid = threadIdx.x, wave = tid >> 6, lane = tid & 63;
  const int n = lane & 15, quad = lane >> 4;
  const int js = blockIdx.y, bh = blockIdx.z;
  const int qrel = blockIdx.x * 512 + wave * 128;

  const ushort* kg = kbuf + (size_t)bh * NPIX * DHEAD;
  const ushort* vg = vTb + (size_t)bh * DHEAD * NPIX;

  bf16x8 qf[8];
#pragma unroll
  for (int rp = 0; rp < 8; ++rp)
    qf[rp] = *(const bf16x8*)(qb +
        ((size_t)bh * NPIX + qrel + rp * 16 + n) * DHEAD + quad * 8);

  f32x4 O[8][2], Ol[8];
#pragma unroll
  for (int rp = 0; rp < 8; ++rp) {
    O[rp][0] = (f32x4){0.f, 0.f, 0.f, 0.f};
    O[rp][1] = (f32x4){0.f, 0.f, 0.f, 0.f};
    Ol[rp]   = (f32x4){0.f, 0.f, 0.f, 0.f};
  }
  const bf16_t one = (bf16_t)1.0f;
  const bf16x8 ones = {one, one, one, one, one, one, one, one};

  // permuted K row: pi(n) = (n>>2)*8 + (n&3); quad gives the d-offset
  const int pk = ((n >> 2) << 3) | (n & 3);
  const ushort* kb0 = kg + (size_t)(js * 1024 + pk) * DHEAD + quad * 8;
  const ushort* vb0 = vg + (size_t)n * NPIX + js * 1024 + quad * 8;

  bf16x8 kA[4], vA[4], kB[4], vB[4];
  ft_load(kb0, vb0, 0, kA, vA);
#pragma unroll 1
  for (int t = 0; t < 16; t += 2) {
    ft_load(kb0, vb0, t + 1, kB, vB);
    ft_compute(qf, kA, vA, ones, O, Ol);
    if (t + 2 < 16) ft_load(kb0, vb0, t + 2, kA, vA);
    ft_compute(qf, kB, vB, ones, O, Ol);
  }

  float* pb = part + ((size_t)js * 65536 + (size_t)bh * NPIX + qrel) * 36;
#pragma unroll
  for (int rp = 0; rp < 8; ++rp)
#pragma unroll
    for (int r = 0; r < 4; ++r) {
      const int q = rp * 16 + quad * 4 + r;
      pb[(size_t)q * 36 + n]      = O[rp][0][r];
      pb[(size_t)q * 36 + 16 + n] = O[rp][1][r];
      if (n == 0) pb[(size_t)q * 36 + 32] = Ol[rp][r];
    }
}

// ---------------------------------------------------------------------------
// out_fused v2: cooperative combine of the 4 key-split f32 partials ONCE per
// block (r10 read part 4x redundantly = 151 MB; now 37.7 MB, each line once),
// normalize, stage bf16 ao in LDS, then out-projection MFMA + bias.
// 512 blocks x 256 thr; block = (batch, 32-px tile); wave = 32 oc x 32 px.
// ---------------------------------------------------------------------------
__global__ void __launch_bounds__(256) out_fused(
    const float* __restrict__ part, const ushort* __restrict__ wo_s,
    const float* __restrict__ bias, float* __restrict__ out) {
  __shared__ ushort AOls[32 * 136];
  const int blk = blockIdx.x, tid = threadIdx.x;
  const int wave = tid >> 6, lane = tid & 63;
  const int n = lane & 15, quad = lane >> 4;
  const int bb = blk >> 7;
  const int p0 = (blk & 127) * 32;
  const int oc0 = wave * 32;

  bf16x8 wf[2][4];
#pragma unroll
  for (int mt = 0; mt < 2; ++mt)
#pragma unroll
    for (int k = 0; k < 4; ++k)
      wf[mt][k] = *(const bf16x8*)(wo_s + (size_t)(((wave * 2 + mt) * 4 + k) * 64 + lane) * 8);

  // cooperative combine: thread = (px8 = tid>>3, c8 = tid&7 -> head, d-half)
  {
    const int px8 = tid >> 3, c8 = tid & 7;
    const int h = c8 >> 1, dh = (c8 & 1) * 16;
    const size_t rowbase = (size_t)(bb * NHEAD + h) * NPIX + p0 + px8;
    float s[16];
#pragma unroll
    for (int e = 0; e < 16; ++e) s[e] = 0.f;
    float l = 0.f;
#pragma unroll
    for (int js = 0; js < 4; ++js) {
      const float* pp = part + ((size_t)js * 65536 + rowbase) * 36;
      f32x4 a0 = *(const f32x4*)(pp + dh);
      f32x4 a1 = *(const f32x4*)(pp + dh + 4);
      f32x4 a2 = *(const f32x4*)(pp + dh + 8);
      f32x4 a3 = *(const f32x4*)(pp + dh + 12);
#pragma unroll
      for (int e = 0; e < 4; ++e) {
        s[e]      += a0[e];
        s[4 + e]  += a1[e];
        s[8 + e]  += a2[e];
        s[12 + e] += a3[e];
      }
      l += pp[32];
    }
    const float inv = 1.f / l;
    bf16x8 o0, o1;
#pragma unroll
    for (int e = 0; e < 8; ++e) {
      o0[e] = (bf16_t)(s[e] * inv);
      o1[e] = (bf16_t)(s[8 + e] * inv);
    }
    ushort* dstl = &AOls[px8 * 136 + (c8 >> 1) * 32 + (c8 & 1) * 16];
    *(bf16x8*)dstl = o0;
    *(bf16x8*)(dstl + 8) = o1;
  }
  __syncthreads();

  bf16x8 bfr[2][4];                    // [nt][k] from LDS (shared, not 4x)
#pragma unroll
  for (int nt = 0; nt < 2; ++nt)
#pragma unroll
    for (int k = 0; k < 4; ++k)
      bfr[nt][k] = *(const bf16x8*)&AOls[(nt * 16 + n) * 136 + k * 32 + quad * 8];

  f32x4 acc[2][2];
#pragma unroll
  for (int mt = 0; mt < 2; ++mt)
#pragma unroll
    for (int nt = 0; nt < 2; ++nt) acc[mt][nt] = (f32x4){0.f, 0.f, 0.f, 0.f};
#pragma unroll
  for (int k = 0; k < 4; ++k)
#pragma unroll
    for (int mt = 0; mt < 2; ++mt)
#pragma unroll
      for (int nt = 0; nt < 2; ++nt)
        acc[mt][nt] = __builtin_amdgcn_mfma_f32_16x16x32_bf16(
            wf[mt][k], bfr[nt][k], acc[mt][nt], 0, 0, 0);

#pragma unroll
  for (int mt = 0; mt < 2; ++mt) {
    const int oc = oc0 + mt * 16 + quad * 4;
#pragma unroll
    for (int nt = 0; nt < 2; ++nt)
#pragma unroll
      for (int r = 0; r < 4; ++r)
        out[((size_t)bb * CIN + oc + r) * NPIX + p0 + nt * 16 + n] =
            acc[mt][nt][r] + bias[oc + r];
  }
}

// ---------------------------------------------------------------------------
extern "C" void kernel_launch(void* const* d_in, const int* in_sizes, int n_in,
                              void* d_out, int out_size, void* d_ws, size_t ws_size,
                              hipStream_t stream) {
  const float* x     = (const float*)d_in[0];   // [4,128,64,64]
  const float* w_qkv = (const float*)d_in[1];   // [384,128]
  const float* w_out = (const float*)d_in[2];   // [128,128]
  const float* b_out = (const float*)d_in[3];   // [128]
  float* out = (float*)d_out;                   // [4,128,64,64]

  // ws (bytes): qb 0 | kb 4M | vT 8M | wq_s 12M (96K) | wo_s +256K (32K)
  //             | part 13M .. 13M+37.75M  (~51 MB total)
  char* base = (char*)d_ws;
  ushort* qb   = (ushort*)base;
  ushort* kb   = (ushort*)(base + (size_t)4 * 1024 * 1024);
  ushort* vT   = (ushort*)(base + (size_t)8 * 1024 * 1024);
  ushort* wq_s = (ushort*)(base + (size_t)12 * 1024 * 1024);
  ushort* wo_s = (ushort*)(base + (size_t)12 * 1024 * 1024 + 256 * 1024);
  float*  part = (float*)(base + (size_t)13 * 1024 * 1024);

  prep_swz<<<dim3(32), 256, 0, stream>>>(w_qkv, w_out, wq_s, wo_s);
  qkv_mfma<<<dim3(512), 256, 0, stream>>>(x, wq_s, qb, kb, vT);
  flash_mfma<<<dim3(8, 4, 16), 256, 0, stream>>>(qb, kb, vT, part);
  out_fused<<<dim3(512), 256, 0, stream>>>(part, wo_s, b_out, out);
}